// Round 1
// baseline (571.930 us; speedup 1.0000x reference)
//
#include <hip/hip_runtime.h>
#include <math.h>

// ---------------- workspace layout (float offsets) ----------------
#define WS_H_OFF      0ull          // [4][1024][2048]
#define WS_XTN_OFF    8388608ull    // [4][1024][1024]  (aliased: logitsT/wT after GEMM1)
#define WS_AG_OFF     12582912ull   // alpha_g transposed [4][8][1024]
#define WS_WSUM_OFF   12615680ull   // [4][8][128]
#define WS_WF_OFF     12619776ull   // wf [4][8][1024]
#define WS_U_OFF      12652544ull   // u  [4][8][128]
#define WS_VFP_OFF    12656640ull   // vf partials [4][8][4][256]
#define WS_VC_OFF     12689408ull   // Vc [4][256][8]
#define WS_WR_OFF     12697600ull   // Wrow [4][256][8]
#define WS_S0_OFF     12705792ull   // s0 [4]

// ---------------- K1: transpose + L2 normalize ----------------
// x [32,1024,16,8] -> xtn[b][m][c], m = t*128 + h*8 + w, row L2-normalized over c
__global__ __launch_bounds__(256) void k_transpose_norm(const float* __restrict__ x,
                                                        float* __restrict__ xtn) {
    int b8 = blockIdx.x;   // 0..31
    int hh = blockIdx.y;   // 0..15
    int tid = threadIdx.x; // 256
    __shared__ float tile[8][1032];
    __shared__ float inv[8];
    const float* src = x + (size_t)b8 * 1024 * 128 + hh * 8;
    #pragma unroll
    for (int r = 0; r < 4; ++r) {
        int c = tid * 4 + r;
        const float* p = src + (size_t)c * 128;
        float4 v0 = *(const float4*)(p);
        float4 v1 = *(const float4*)(p + 4);
        tile[0][c] = v0.x; tile[1][c] = v0.y; tile[2][c] = v0.z; tile[3][c] = v0.w;
        tile[4][c] = v1.x; tile[5][c] = v1.y; tile[6][c] = v1.z; tile[7][c] = v1.w;
    }
    __syncthreads();
    int w = tid >> 5, j = tid & 31;
    float s = 0.f;
    #pragma unroll 8
    for (int i = 0; i < 32; ++i) { float v = tile[w][i * 32 + j]; s += v * v; }
    #pragma unroll
    for (int m = 16; m; m >>= 1) s += __shfl_xor(s, m);
    if (j == 0) inv[w] = 1.0f / fmaxf(sqrtf(s), 1e-12f);
    __syncthreads();
    int b = b8 >> 3, t = b8 & 7;
    for (int w2 = 0; w2 < 8; ++w2) {
        int m = t * 128 + hh * 8 + w2;
        float sc = inv[w2];
        float* dst = xtn + ((size_t)b * 1024 + m) * 1024;
        for (int c = tid; c < 1024; c += 256) dst[c] = tile[w2][c] * sc;
    }
}

// ---------------- K2: generic BT GEMM: C[i,j] = sum_k A[i,k]*B[j,k] (+bias) ----------------
#define BI 64
#define BJ 64
#define BKT 16
__global__ __launch_bounds__(256) void k_gemm_bt(
    const float* __restrict__ A, const float* __restrict__ B,
    float* __restrict__ C, const float* __restrict__ bias,
    int MI, int NJ, int Kd, int biasMode,
    long long Astr, long long Bstr, long long Cstr)
{
    int bz = blockIdx.z;
    A += (size_t)bz * Astr; B += (size_t)bz * Bstr; C += (size_t)bz * Cstr;
    int i0 = blockIdx.y * BI, j0 = blockIdx.x * BJ;
    int tid = threadIdx.x;
    __shared__ __align__(16) float As[BKT][BI + 4];
    __shared__ __align__(16) float Bs[BKT][BJ + 4];
    float acc[4][4] = {};
    int ty = tid >> 4, tx = tid & 15;
    int li = tid >> 2, lk = (tid & 3) * 4;
    for (int kt = 0; kt < Kd; kt += BKT) {
        float4 av = *(const float4*)(A + (size_t)(i0 + li) * Kd + kt + lk);
        float4 bv = *(const float4*)(B + (size_t)(j0 + li) * Kd + kt + lk);
        As[lk + 0][li] = av.x; As[lk + 1][li] = av.y; As[lk + 2][li] = av.z; As[lk + 3][li] = av.w;
        Bs[lk + 0][li] = bv.x; Bs[lk + 1][li] = bv.y; Bs[lk + 2][li] = bv.z; Bs[lk + 3][li] = bv.w;
        __syncthreads();
        #pragma unroll
        for (int kk = 0; kk < BKT; ++kk) {
            float4 a = *(const float4*)&As[kk][ty * 4];
            float4 b = *(const float4*)&Bs[kk][tx * 4];
            float ar[4] = {a.x, a.y, a.z, a.w};
            float br[4] = {b.x, b.y, b.z, b.w};
            #pragma unroll
            for (int r = 0; r < 4; ++r)
                #pragma unroll
                for (int c = 0; c < 4; ++c) acc[r][c] += ar[r] * br[c];
        }
        __syncthreads();
    }
    #pragma unroll
    for (int r = 0; r < 4; ++r) {
        int i = i0 + ty * 4 + r;
        float rowb = (biasMode == 2) ? bias[i] : 0.f;
        float vals[4];
        #pragma unroll
        for (int c = 0; c < 4; ++c) {
            float v = acc[r][c] + rowb;
            if (biasMode == 1) v += bias[j0 + tx * 4 + c];
            vals[c] = v;
        }
        float4 o; o.x = vals[0]; o.y = vals[1]; o.z = vals[2]; o.w = vals[3];
        *(float4*)(C + (size_t)i * NJ + j0 + tx * 4) = o;
    }
}

// ---------------- K3: alpha_g = sigmoid(h @ W_g^T + b_g), stored transposed [b][g][m] ----------------
__global__ void k_alpha_g(const float* __restrict__ h, const float* __restrict__ Wg,
                          const float* __restrict__ bg, float* __restrict__ agT) {
    int bm = blockIdx.x;     // 0..4095
    int lane = threadIdx.x;  // 64
    const float* hr = h + (size_t)bm * 2048;
    float acc[8] = {};
    for (int c = lane; c < 2048; c += 64) {
        float hv = hr[c];
        #pragma unroll
        for (int g = 0; g < 8; ++g) acc[g] += hv * Wg[g * 2048 + c];
    }
    int b = bm >> 10, m = bm & 1023;
    #pragma unroll
    for (int g = 0; g < 8; ++g) {
        float tot = acc[g];
        #pragma unroll
        for (int mm = 32; mm; mm >>= 1) tot += __shfl_xor(tot, mm);
        if (lane == g) {
            float v = tot + bg[g];
            agT[((size_t)b * 8 + g) * 1024 + m] = 1.f / (1.f + expf(-v));
        }
    }
}

// ---------------- K4: softmax over m (row of logitsT), * alpha_g, in-place; wsum ----------------
__global__ __launch_bounds__(256) void k_softmax(float* __restrict__ lt,
                                                 const float* __restrict__ agT,
                                                 float* __restrict__ wsum) {
    int gk = blockIdx.x, b = blockIdx.y;
    int tid = threadIdx.x;
    float* row = lt + ((size_t)b * 1024 + gk) * 1024;
    int g = gk >> 7;
    const float* ag = agT + ((size_t)b * 8 + g) * 1024;
    __shared__ float red[4], red2[4], red3[4];
    float4 v = *(const float4*)(row + tid * 4);
    float mx = fmaxf(fmaxf(v.x, v.y), fmaxf(v.z, v.w));
    #pragma unroll
    for (int m = 32; m; m >>= 1) mx = fmaxf(mx, __shfl_xor(mx, m));
    if ((tid & 63) == 0) red[tid >> 6] = mx;
    __syncthreads();
    mx = fmaxf(fmaxf(red[0], red[1]), fmaxf(red[2], red[3]));
    float e0 = expf(v.x - mx), e1 = expf(v.y - mx), e2 = expf(v.z - mx), e3 = expf(v.w - mx);
    float s = e0 + e1 + e2 + e3;
    #pragma unroll
    for (int m = 32; m; m >>= 1) s += __shfl_xor(s, m);
    if ((tid & 63) == 0) red2[tid >> 6] = s;
    __syncthreads();
    s = red2[0] + red2[1] + red2[2] + red2[3];
    float invs = 1.f / s;
    float4 a = *(const float4*)(ag + tid * 4);
    float w0 = e0 * invs * a.x, w1 = e1 * invs * a.y, w2 = e2 * invs * a.z, w3 = e3 * invs * a.w;
    float4 o; o.x = w0; o.y = w1; o.z = w2; o.w = w3;
    *(float4*)(row + tid * 4) = o;
    float t = w0 + w1 + w2 + w3;
    #pragma unroll
    for (int m = 32; m; m >>= 1) t += __shfl_xor(t, m);
    if ((tid & 63) == 0) red3[tid >> 6] = t;
    __syncthreads();
    if (tid == 0) wsum[((size_t)b * 8 + g) * 128 + (gk & 127)] = red3[0] + red3[1] + red3[2] + red3[3];
}

// ---------------- K4b: wf[b,g,m] = sum_k Wf[k]*w[b,gk,m];  u = Wf*wsum ----------------
__global__ __launch_bounds__(256) void k_wf_u(const float* __restrict__ wT,
                                              const float* __restrict__ wsum,
                                              const float* __restrict__ Wf,
                                              float* __restrict__ wf, float* __restrict__ u) {
    int bg = blockIdx.x;  // 0..31
    int tid = threadIdx.x;
    __shared__ float wfl[128];
    if (tid < 128) {
        wfl[tid] = Wf[tid];
        u[bg * 128 + tid] = Wf[tid] * wsum[bg * 128 + tid];
    }
    __syncthreads();
    const float* base = wT + (size_t)bg * 128 * 1024;
    float acc[4] = {};
    for (int k = 0; k < 128; ++k) {
        float wfk = wfl[k];
        const float* r = base + (size_t)k * 1024;
        #pragma unroll
        for (int q = 0; q < 4; ++q) acc[q] += wfk * r[tid + q * 256];
    }
    #pragma unroll
    for (int q = 0; q < 4; ++q) wf[(size_t)bg * 1024 + tid + q * 256] = acc[q];
}

// ---------------- K5: vf partial = sum_{m in chunk} wf[m]*h[b,m,g*256+d] ----------------
__global__ __launch_bounds__(256) void k_vf_partial(const float* __restrict__ h,
                                                    const float* __restrict__ wf,
                                                    float* __restrict__ vfp) {
    int mc = blockIdx.x, g = blockIdx.y, b = blockIdx.z;
    int d = threadIdx.x;
    __shared__ float wl[256];
    wl[d] = wf[((size_t)b * 8 + g) * 1024 + mc * 256 + d];
    __syncthreads();
    const float* hb = h + (size_t)b * 1024 * 2048 + (size_t)(mc * 256) * 2048 + g * 256;
    float acc = 0.f;
    #pragma unroll 8
    for (int m = 0; m < 256; ++m) acc += wl[m] * hb[(size_t)m * 2048 + d];
    vfp[(((size_t)(b * 8 + g)) * 4 + mc) * 256 + d] = acc;
}

// ---------------- K6: finalize vf, center, trace, S(8x8), rank-8 Newton-Schulz ----------------
#define MM8(DST, P, Q) do { if (act) { float s_ = 0.f; \
    _Pragma("unroll") \
    for (int l_ = 0; l_ < 8; ++l_) s_ += P[ii][l_] * Q[l_][jj]; \
    DST[ii][jj] = s_; } __syncthreads(); } while (0)

__global__ __launch_bounds__(256) void k_finalize(const float* __restrict__ vfp,
                                                  const float* __restrict__ u,
                                                  const float* __restrict__ cent,
                                                  const float* __restrict__ bf,
                                                  float* __restrict__ VcOut,
                                                  float* __restrict__ Wrow,
                                                  float* __restrict__ s0) {
    int b = blockIdx.x;
    int tid = threadIdx.x;  // 256
    __shared__ float ul[8][128];
    __shared__ float Vl[256][9];
    __shared__ float red[256];
    __shared__ float Sm[8][8], W1[8][8], W2[8][8], YmL[8][8], ZmL[8][8], ZYL[8][8], FmL[8][8];
    for (int i = tid; i < 1024; i += 256) ul[i >> 7][i & 127] = u[b * 1024 + i];
    __syncthreads();
    int d = tid;
    float bfv = bf[0];
    float vfl[8];
    #pragma unroll
    for (int g = 0; g < 8; ++g) {
        float acc = 0.f;
        #pragma unroll
        for (int mc = 0; mc < 4; ++mc) acc += vfp[(((size_t)(b * 8 + g)) * 4 + mc) * 256 + d];
        float ct = 0.f;
        for (int k = 0; k < 128; ++k) ct += ul[g][k] * cent[k * 256 + d];
        vfl[g] = acc - ct + bfv;
    }
    float mean = 0.f;
    #pragma unroll
    for (int g = 0; g < 8; ++g) mean += vfl[g];
    mean *= 0.125f;
    float trp = 0.f;
    #pragma unroll
    for (int g = 0; g < 8; ++g) { float v = vfl[g] - mean; Vl[d][g] = v; trp += v * v; }
    red[tid] = trp;
    __syncthreads();
    for (int s = 128; s > 0; s >>= 1) { if (tid < s) red[tid] += red[tid + s]; __syncthreads(); }
    float tr = red[0] * 0.125f;  // trace(cov)
    bool act = tid < 64;
    int ii = (tid >> 3) & 7, jj = tid & 7;
    if (act) {
        float sv = 0.f;
        for (int dd = 0; dd < 256; ++dd) sv += Vl[dd][ii] * Vl[dd][jj];
        Sm[ii][jj] = sv / (8.f * tr);
    }
    __syncthreads();
    // representation: mat = a*I + U B U^T, S = U^T U; product (a,P)(c,Q)=(ac, aQ+cP+P S Q)
    if (act) {
        YmL[ii][jj] = (ii == jj ? 1.5f : 0.f) - 0.5f * Sm[ii][jj];  // Y = A@(1.5I-0.5A): B-part
        ZmL[ii][jj] = (ii == jj ? -0.5f : 0.f);                      // Z = 1.5I - 0.5A
    }
    __syncthreads();
    float ya = 0.f, za = 1.5f;
    // one NS loop iteration (ITERN=3)
    MM8(W1, Sm, YmL);
    MM8(W2, ZmL, W1);
    float pa = za * ya;
    if (act) ZYL[ii][jj] = -0.5f * (za * YmL[ii][jj] + ya * ZmL[ii][jj] + W2[ii][jj]);
    __syncthreads();
    float zya = 1.5f - 0.5f * pa;
    MM8(W1, Sm, ZYL);
    MM8(W2, YmL, W1);
    if (act) YmL[ii][jj] = ya * ZYL[ii][jj] + zya * YmL[ii][jj] + W2[ii][jj];
    __syncthreads();
    ya = ya * zya;
    MM8(W1, Sm, ZmL);
    MM8(W2, ZYL, W1);
    if (act) ZmL[ii][jj] = zya * ZmL[ii][jj] + za * ZYL[ii][jj] + W2[ii][jj];
    __syncthreads();
    za = zya * za;
    // final: ZYf = 0.5 * Y @ (3I - Z@Y)
    MM8(W1, Sm, YmL);
    MM8(W2, ZmL, W1);
    float p2a = za * ya;
    if (act) ZYL[ii][jj] = za * YmL[ii][jj] + ya * ZmL[ii][jj] + W2[ii][jj];  // P2
    __syncthreads();
    MM8(W1, Sm, ZYL);
    MM8(W2, YmL, W1);
    if (act) FmL[ii][jj] = 0.5f * ((3.f - p2a) * YmL[ii][jj] - ya * ZYL[ii][jj] - W2[ii][jj]);
    __syncthreads();
    float fa = 0.5f * ya * (3.f - p2a);
    float sqtr = sqrtf(tr);
    float scaleF = 1.f / (8.f * sqtr);  // sqrt(tr)/(8*tr)
    // Wrow[d][j] = sum_i Vc[d][i]*Fm[i][j]*scaleF
    #pragma unroll
    for (int jo = 0; jo < 8; ++jo) {
        float sv = 0.f;
        #pragma unroll
        for (int i = 0; i < 8; ++i) sv += Vl[d][i] * FmL[i][jo];
        Wrow[((size_t)b * 256 + d) * 8 + jo] = sv * scaleF;
    }
    #pragma unroll
    for (int jo = 0; jo < 8; ++jo) VcOut[((size_t)b * 256 + d) * 8 + jo] = Vl[d][jo];
    if (tid == 0) s0[b] = fa * sqtr;
}

// ---------------- K7: triuvec output: R[d,e] = s0*delta + Wrow[d,:].Vc[e,:] ----------------
__global__ __launch_bounds__(256) void k_output(const float* __restrict__ Vc,
                                                const float* __restrict__ Wrow,
                                                const float* __restrict__ s0,
                                                float* __restrict__ out) {
    int dd = blockIdx.x, b = blockIdx.y;
    int e = threadIdx.x;
    __shared__ float Vl[256][9];
    __shared__ float wr[8];
    float4 v0 = *(const float4*)(Vc + ((size_t)b * 256 + e) * 8);
    float4 v1 = *(const float4*)(Vc + ((size_t)b * 256 + e) * 8 + 4);
    Vl[e][0] = v0.x; Vl[e][1] = v0.y; Vl[e][2] = v0.z; Vl[e][3] = v0.w;
    Vl[e][4] = v1.x; Vl[e][5] = v1.y; Vl[e][6] = v1.z; Vl[e][7] = v1.w;
    if (e < 8) wr[e] = Wrow[((size_t)b * 256 + dd) * 8 + e];
    __syncthreads();
    if (e >= dd) {
        float v = (e == dd) ? s0[b] : 0.f;
        #pragma unroll
        for (int j = 0; j < 8; ++j) v += wr[j] * Vl[e][j];
        size_t idx = (size_t)b * 32896 + (size_t)dd * 256 - ((size_t)dd * (dd - 1)) / 2 + (e - dd);
        out[idx] = v;
    }
}

extern "C" void kernel_launch(void* const* d_in, const int* in_sizes, int n_in,
                              void* d_out, int out_size, void* d_ws, size_t ws_size,
                              hipStream_t stream) {
    const float* x    = (const float*)d_in[0];
    const float* cent = (const float*)d_in[1];
    const float* Winp = (const float*)d_in[2];
    const float* binp = (const float*)d_in[3];
    const float* Wg   = (const float*)d_in[4];
    const float* bg   = (const float*)d_in[5];
    const float* Wgk  = (const float*)d_in[6];
    const float* Wf   = (const float*)d_in[8];
    const float* bf   = (const float*)d_in[9];
    float* out = (float*)d_out;
    float* ws  = (float*)d_ws;

    float* h    = ws + WS_H_OFF;
    float* xtn  = ws + WS_XTN_OFF;
    float* lt   = xtn;  // alias: xtn dead after GEMM1
    float* agT  = ws + WS_AG_OFF;
    float* wsum = ws + WS_WSUM_OFF;
    float* wf   = ws + WS_WF_OFF;
    float* u    = ws + WS_U_OFF;
    float* vfp  = ws + WS_VFP_OFF;
    float* Vc   = ws + WS_VC_OFF;
    float* Wr   = ws + WS_WR_OFF;
    float* s0   = ws + WS_S0_OFF;

    k_transpose_norm<<<dim3(32, 16), 256, 0, stream>>>(x, xtn);
    // h[bm,j] = xtn @ W_inp^T + b_inp  (col bias)
    k_gemm_bt<<<dim3(2048 / 64, 4096 / 64, 1), 256, 0, stream>>>(
        xtn, Winp, h, binp, 4096, 2048, 1024, 1, 0, 0, 0);
    k_alpha_g<<<4096, 64, 0, stream>>>(h, Wg, bg, agT);
    // logitsT[b][gk][m] = W_gk @ h_b^T  (bias omitted: softmax over m is shift-invariant)
    k_gemm_bt<<<dim3(1024 / 64, 1024 / 64, 4), 256, 0, stream>>>(
        Wgk, h, lt, nullptr, 1024, 1024, 2048, 0, 0, 2097152, 1048576);
    k_softmax<<<dim3(1024, 4), 256, 0, stream>>>(lt, agT, wsum);
    k_wf_u<<<32, 256, 0, stream>>>(lt, wsum, Wf, wf, u);
    k_vf_partial<<<dim3(4, 8, 4), 256, 0, stream>>>(h, wf, vfp);
    k_finalize<<<4, 256, 0, stream>>>(vfp, u, cent, bf, Vc, Wr, s0);
    k_output<<<dim3(256, 4), 256, 0, stream>>>(Vc, Wr, s0, out);
}

// Round 2
// 177.804 us; speedup vs baseline: 3.2166x; 3.2166x over previous
//
#include <hip/hip_runtime.h>
#include <math.h>

typedef float f32x4 __attribute__((ext_vector_type(4)));
typedef short bf16x8 __attribute__((ext_vector_type(8)));
typedef unsigned short u16;

__device__ __forceinline__ u16 f2bf(float f) {
    unsigned u = __builtin_bit_cast(unsigned, f);
    u += 0x7fff + ((u >> 16) & 1);   // RNE
    return (u16)(u >> 16);
}
__device__ __forceinline__ float bf2f(u16 s) {
    unsigned v = ((unsigned)s) << 16;
    return __builtin_bit_cast(float, v);
}
__device__ __forceinline__ void gload16(const void* g, void* l) {
    __builtin_amdgcn_global_load_lds(
        (const __attribute__((address_space(1))) unsigned int*)g,
        (__attribute__((address_space(3))) unsigned int*)l, 16, 0, 0);
}

// ---------------- K0: f32 -> bf16 convert ----------------
__global__ __launch_bounds__(256) void k_f2bf(const float* __restrict__ in,
                                              u16* __restrict__ out, int n) {
    int i = (blockIdx.x * 256 + threadIdx.x) * 4;
    if (i < n) {
        float4 v = *(const float4*)(in + i);
        ushort4 o;
        o.x = f2bf(v.x); o.y = f2bf(v.y); o.z = f2bf(v.z); o.w = f2bf(v.w);
        *(ushort4*)(out + i) = o;
    }
}

// ---------------- K1: transpose + L2 normalize -> bf16 ----------------
// x [32,1024,16,8] -> xtn[b][m][c] bf16, m = t*128 + h*8 + w, row L2-normalized over c
__global__ __launch_bounds__(256) void k_transpose_norm(const float* __restrict__ x,
                                                        u16* __restrict__ xtn) {
    int b8 = blockIdx.x;   // 0..31
    int hh = blockIdx.y;   // 0..15
    int tid = threadIdx.x; // 256
    __shared__ float tile[8][1032];
    __shared__ float inv[8];
    const float* src = x + (size_t)b8 * 1024 * 128 + hh * 8;
    #pragma unroll
    for (int r = 0; r < 4; ++r) {
        int c = tid * 4 + r;
        const float* p = src + (size_t)c * 128;
        float4 v0 = *(const float4*)(p);
        float4 v1 = *(const float4*)(p + 4);
        tile[0][c] = v0.x; tile[1][c] = v0.y; tile[2][c] = v0.z; tile[3][c] = v0.w;
        tile[4][c] = v1.x; tile[5][c] = v1.y; tile[6][c] = v1.z; tile[7][c] = v1.w;
    }
    __syncthreads();
    int w = tid >> 5, j = tid & 31;
    float s = 0.f;
    #pragma unroll 8
    for (int i = 0; i < 32; ++i) { float v = tile[w][i * 32 + j]; s += v * v; }
    #pragma unroll
    for (int m = 16; m; m >>= 1) s += __shfl_xor(s, m);
    if (j == 0) inv[w] = 1.0f / fmaxf(sqrtf(s), 1e-12f);
    __syncthreads();
    int b = b8 >> 3, t = b8 & 7;
    int c0 = tid * 4;
    for (int w2 = 0; w2 < 8; ++w2) {
        int m = t * 128 + hh * 8 + w2;
        float sc = inv[w2];
        u16* dst = xtn + ((size_t)b * 1024 + m) * 1024;
        ushort4 o;
        o.x = f2bf(tile[w2][c0 + 0] * sc);
        o.y = f2bf(tile[w2][c0 + 1] * sc);
        o.z = f2bf(tile[w2][c0 + 2] * sc);
        o.w = f2bf(tile[w2][c0 + 3] * sc);
        *(ushort4*)(dst + c0) = o;
    }
}

// ---------------- K2: bf16 MFMA GEMM (BT): C[i,j] = sum_k A[i,k]*B[j,k] ----------------
// 128x128 tile, 4 waves 2x2 (64x64 each), K_STEP=32, mfma_f32_16x16x32_bf16.
// MODE 0: f32 out, no bias.  MODE 1: bf16 out + column bias.
template <int MODE>
__global__ __launch_bounds__(256) void k_mfma_gemm(
    const u16* __restrict__ A, const u16* __restrict__ B,
    float* __restrict__ Cf, u16* __restrict__ Cb,
    const float* __restrict__ bias, int K, int N,
    long long Bstr, long long Cstr)
{
    int bz = blockIdx.z;
    B += (size_t)bz * Bstr;
    int tid = threadIdx.x, lane = tid & 63, wave = tid >> 6;
    int wr = wave >> 1, wc = wave & 1;
    int i0 = blockIdx.y * 128, j0 = blockIdx.x * 128;
    __shared__ u16 As[2][128 * 32];
    __shared__ u16 Bs[2][128 * 32];
    f32x4 acc[4][4] = {};
    int lrow = lane >> 2, lk = (lane & 3) * 8;
    int fr = lane & 15, fg = lane >> 4;

    auto stage = [&](int buf, int kt) {
        #pragma unroll
        for (int q = 0; q < 2; ++q) {
            int blk = q * 4 + wave;  // 16-row block of the 128-row tile
            gload16(A + (size_t)(i0 + blk * 16 + lrow) * K + kt + lk, &As[buf][blk * 512]);
            gload16(B + (size_t)(j0 + blk * 16 + lrow) * K + kt + lk, &Bs[buf][blk * 512]);
        }
    };
    auto compute = [&](int buf) {
        bf16x8 af[4], bv[4];
        #pragma unroll
        for (int mi = 0; mi < 4; ++mi)
            af[mi] = *(const bf16x8*)&As[buf][(wr * 64 + mi * 16 + fr) * 32 + fg * 8];
        #pragma unroll
        for (int ni = 0; ni < 4; ++ni)
            bv[ni] = *(const bf16x8*)&Bs[buf][(wc * 64 + ni * 16 + fr) * 32 + fg * 8];
        #pragma unroll
        for (int mi = 0; mi < 4; ++mi)
            #pragma unroll
            for (int ni = 0; ni < 4; ++ni)
                acc[mi][ni] = __builtin_amdgcn_mfma_f32_16x16x32_bf16(
                    af[mi], bv[ni], acc[mi][ni], 0, 0, 0);
    };

    stage(0, 0);
    __syncthreads();
    int nk = K >> 5, cur = 0;
    for (int t = 0; t < nk - 1; ++t) {
        stage(cur ^ 1, (t + 1) << 5);  // prefetch next tile (in flight under MFMA)
        compute(cur);
        __syncthreads();               // vmcnt(0)+barrier: next tile ready, cur reusable
        cur ^= 1;
    }
    compute(cur);

    // epilogue: C/D layout col = lane&15, row = (lane>>4)*4 + r  [m89]
    if (MODE == 1) {
        #pragma unroll
        for (int ni = 0; ni < 4; ++ni) {
            int col = j0 + wc * 64 + ni * 16 + fr;
            float bvv = bias[col];
            #pragma unroll
            for (int mi = 0; mi < 4; ++mi)
                #pragma unroll
                for (int r = 0; r < 4; ++r) {
                    int row = i0 + wr * 64 + mi * 16 + fg * 4 + r;
                    Cb[(size_t)row * N + col] = f2bf(acc[mi][ni][r] + bvv);
                }
        }
    } else {
        float* C2 = Cf + (size_t)bz * Cstr;
        #pragma unroll
        for (int ni = 0; ni < 4; ++ni) {
            int col = j0 + wc * 64 + ni * 16 + fr;
            #pragma unroll
            for (int mi = 0; mi < 4; ++mi)
                #pragma unroll
                for (int r = 0; r < 4; ++r) {
                    int row = i0 + wr * 64 + mi * 16 + fg * 4 + r;
                    C2[(size_t)row * N + col] = acc[mi][ni][r];
                }
        }
    }
}

// ---------------- K3: alpha_g = sigmoid(h @ W_g^T + b_g), stored transposed [b][g][m] ----------------
__global__ void k_alpha_g(const u16* __restrict__ h, const float* __restrict__ Wg,
                          const float* __restrict__ bg, float* __restrict__ agT) {
    int bm = blockIdx.x;     // 0..4095
    int lane = threadIdx.x;  // 64
    const u16* hr = h + (size_t)bm * 2048;
    float acc[8] = {};
    for (int c = lane; c < 2048; c += 64) {
        float hv = bf2f(hr[c]);
        #pragma unroll
        for (int g = 0; g < 8; ++g) acc[g] += hv * Wg[g * 2048 + c];
    }
    int b = bm >> 10, m = bm & 1023;
    #pragma unroll
    for (int g = 0; g < 8; ++g) {
        float tot = acc[g];
        #pragma unroll
        for (int mm = 32; mm; mm >>= 1) tot += __shfl_xor(tot, mm);
        if (lane == g) {
            float v = tot + bg[g];
            agT[((size_t)b * 8 + g) * 1024 + m] = 1.f / (1.f + expf(-v));
        }
    }
}

// ---------------- K4: softmax over m (row of logitsT), * alpha_g, in-place; wsum ----------------
__global__ __launch_bounds__(256) void k_softmax(float* __restrict__ lt,
                                                 const float* __restrict__ agT,
                                                 float* __restrict__ wsum) {
    int gk = blockIdx.x, b = blockIdx.y;
    int tid = threadIdx.x;
    float* row = lt + ((size_t)b * 1024 + gk) * 1024;
    int g = gk >> 7;
    const float* ag = agT + ((size_t)b * 8 + g) * 1024;
    __shared__ float red[4], red2[4], red3[4];
    float4 v = *(const float4*)(row + tid * 4);
    float mx = fmaxf(fmaxf(v.x, v.y), fmaxf(v.z, v.w));
    #pragma unroll
    for (int m = 32; m; m >>= 1) mx = fmaxf(mx, __shfl_xor(mx, m));
    if ((tid & 63) == 0) red[tid >> 6] = mx;
    __syncthreads();
    mx = fmaxf(fmaxf(red[0], red[1]), fmaxf(red[2], red[3]));
    float e0 = expf(v.x - mx), e1 = expf(v.y - mx), e2 = expf(v.z - mx), e3 = expf(v.w - mx);
    float s = e0 + e1 + e2 + e3;
    #pragma unroll
    for (int m = 32; m; m >>= 1) s += __shfl_xor(s, m);
    if ((tid & 63) == 0) red2[tid >> 6] = s;
    __syncthreads();
    s = red2[0] + red2[1] + red2[2] + red2[3];
    float invs = 1.f / s;
    float4 a = *(const float4*)(ag + tid * 4);
    float w0 = e0 * invs * a.x, w1 = e1 * invs * a.y, w2 = e2 * invs * a.z, w3 = e3 * invs * a.w;
    float4 o; o.x = w0; o.y = w1; o.z = w2; o.w = w3;
    *(float4*)(row + tid * 4) = o;
    float t = w0 + w1 + w2 + w3;
    #pragma unroll
    for (int m = 32; m; m >>= 1) t += __shfl_xor(t, m);
    if ((tid & 63) == 0) red3[tid >> 6] = t;
    __syncthreads();
    if (tid == 0) wsum[((size_t)b * 8 + g) * 128 + (gk & 127)] = red3[0] + red3[1] + red3[2] + red3[3];
}

// ---------------- K4b: wf[b,g,m] = sum_k Wf[k]*w[b,gk,m];  u = Wf*wsum ----------------
__global__ __launch_bounds__(256) void k_wf_u(const float* __restrict__ wT,
                                              const float* __restrict__ wsum,
                                              const float* __restrict__ Wf,
                                              float* __restrict__ wf, float* __restrict__ u) {
    int bg = blockIdx.x;  // 0..31
    int tid = threadIdx.x;
    __shared__ float wfl[128];
    if (tid < 128) {
        wfl[tid] = Wf[tid];
        u[bg * 128 + tid] = Wf[tid] * wsum[bg * 128 + tid];
    }
    __syncthreads();
    const float* base = wT + (size_t)bg * 128 * 1024;
    float acc[4] = {};
    for (int k = 0; k < 128; ++k) {
        float wfk = wfl[k];
        const float* r = base + (size_t)k * 1024;
        #pragma unroll
        for (int q = 0; q < 4; ++q) acc[q] += wfk * r[tid + q * 256];
    }
    #pragma unroll
    for (int q = 0; q < 4; ++q) wf[(size_t)bg * 1024 + tid + q * 256] = acc[q];
}

// ---------------- K5: vf partial = sum_{m in chunk} wf[m]*h[b,m,g*256+d] ----------------
__global__ __launch_bounds__(256) void k_vf_partial(const u16* __restrict__ h,
                                                    const float* __restrict__ wf,
                                                    float* __restrict__ vfp) {
    int mc = blockIdx.x, g = blockIdx.y, b = blockIdx.z;
    int d = threadIdx.x;
    __shared__ float wl[256];
    wl[d] = wf[((size_t)b * 8 + g) * 1024 + mc * 256 + d];
    __syncthreads();
    const u16* hb = h + (size_t)b * 1024 * 2048 + (size_t)(mc * 256) * 2048 + g * 256;
    float acc = 0.f;
    #pragma unroll 8
    for (int m = 0; m < 256; ++m) acc += wl[m] * bf2f(hb[(size_t)m * 2048 + d]);
    vfp[(((size_t)(b * 8 + g)) * 4 + mc) * 256 + d] = acc;
}

// ---------------- K6: finalize vf, center, trace, S(8x8), rank-8 Newton-Schulz ----------------
#define MM8(DST, P, Q) do { if (act) { float s_ = 0.f; \
    _Pragma("unroll") \
    for (int l_ = 0; l_ < 8; ++l_) s_ += P[ii][l_] * Q[l_][jj]; \
    DST[ii][jj] = s_; } __syncthreads(); } while (0)

__global__ __launch_bounds__(256) void k_finalize(const float* __restrict__ vfp,
                                                  const float* __restrict__ u,
                                                  const float* __restrict__ cent,
                                                  const float* __restrict__ bf,
                                                  float* __restrict__ VcOut,
                                                  float* __restrict__ Wrow,
                                                  float* __restrict__ s0) {
    int b = blockIdx.x;
    int tid = threadIdx.x;  // 256
    __shared__ float ul[8][128];
    __shared__ float Vl[256][9];
    __shared__ float red[256];
    __shared__ float Sm[8][8], W1[8][8], W2[8][8], YmL[8][8], ZmL[8][8], ZYL[8][8], FmL[8][8];
    for (int i = tid; i < 1024; i += 256) ul[i >> 7][i & 127] = u[b * 1024 + i];
    __syncthreads();
    int d = tid;
    float bfv = bf[0];
    float vfl[8];
    #pragma unroll
    for (int g = 0; g < 8; ++g) {
        float acc = 0.f;
        #pragma unroll
        for (int mc = 0; mc < 4; ++mc) acc += vfp[(((size_t)(b * 8 + g)) * 4 + mc) * 256 + d];
        float ct = 0.f;
        for (int k = 0; k < 128; ++k) ct += ul[g][k] * cent[k * 256 + d];
        vfl[g] = acc - ct + bfv;
    }
    float mean = 0.f;
    #pragma unroll
    for (int g = 0; g < 8; ++g) mean += vfl[g];
    mean *= 0.125f;
    float trp = 0.f;
    #pragma unroll
    for (int g = 0; g < 8; ++g) { float v = vfl[g] - mean; Vl[d][g] = v; trp += v * v; }
    red[tid] = trp;
    __syncthreads();
    for (int s = 128; s > 0; s >>= 1) { if (tid < s) red[tid] += red[tid + s]; __syncthreads(); }
    float tr = red[0] * 0.125f;  // trace(cov)
    bool act = tid < 64;
    int ii = (tid >> 3) & 7, jj = tid & 7;
    if (act) {
        float sv = 0.f;
        for (int dd = 0; dd < 256; ++dd) sv += Vl[dd][ii] * Vl[dd][jj];
        Sm[ii][jj] = sv / (8.f * tr);
    }
    __syncthreads();
    // representation: mat = a*I + U B U^T, S = U^T U; product (a,P)(c,Q)=(ac, aQ+cP+P S Q)
    if (act) {
        YmL[ii][jj] = (ii == jj ? 1.5f : 0.f) - 0.5f * Sm[ii][jj];
        ZmL[ii][jj] = (ii == jj ? -0.5f : 0.f);
    }
    __syncthreads();
    float ya = 0.f, za = 1.5f;
    MM8(W1, Sm, YmL);
    MM8(W2, ZmL, W1);
    float pa = za * ya;
    if (act) ZYL[ii][jj] = -0.5f * (za * YmL[ii][jj] + ya * ZmL[ii][jj] + W2[ii][jj]);
    __syncthreads();
    float zya = 1.5f - 0.5f * pa;
    MM8(W1, Sm, ZYL);
    MM8(W2, YmL, W1);
    if (act) YmL[ii][jj] = ya * ZYL[ii][jj] + zya * YmL[ii][jj] + W2[ii][jj];
    __syncthreads();
    ya = ya * zya;
    MM8(W1, Sm, ZmL);
    MM8(W2, ZYL, W1);
    if (act) ZmL[ii][jj] = zya * ZmL[ii][jj] + za * ZYL[ii][jj] + W2[ii][jj];
    __syncthreads();
    za = zya * za;
    MM8(W1, Sm, YmL);
    MM8(W2, ZmL, W1);
    float p2a = za * ya;
    if (act) ZYL[ii][jj] = za * YmL[ii][jj] + ya * ZmL[ii][jj] + W2[ii][jj];
    __syncthreads();
    MM8(W1, Sm, ZYL);
    MM8(W2, YmL, W1);
    if (act) FmL[ii][jj] = 0.5f * ((3.f - p2a) * YmL[ii][jj] - ya * ZYL[ii][jj] - W2[ii][jj]);
    __syncthreads();
    float fa = 0.5f * ya * (3.f - p2a);
    float sqtr = sqrtf(tr);
    float scaleF = 1.f / (8.f * sqtr);
    #pragma unroll
    for (int jo = 0; jo < 8; ++jo) {
        float sv = 0.f;
        #pragma unroll
        for (int i = 0; i < 8; ++i) sv += Vl[d][i] * FmL[i][jo];
        Wrow[((size_t)b * 256 + d) * 8 + jo] = sv * scaleF;
    }
    #pragma unroll
    for (int jo = 0; jo < 8; ++jo) VcOut[((size_t)b * 256 + d) * 8 + jo] = Vl[d][jo];
    if (tid == 0) s0[b] = fa * sqtr;
}

// ---------------- K7: triuvec output: R[d,e] = s0*delta + Wrow[d,:].Vc[e,:] ----------------
__global__ __launch_bounds__(256) void k_output(const float* __restrict__ Vc,
                                                const float* __restrict__ Wrow,
                                                const float* __restrict__ s0,
                                                float* __restrict__ out) {
    int dd = blockIdx.x, b = blockIdx.y;
    int e = threadIdx.x;
    __shared__ float Vl[256][9];
    __shared__ float wr[8];
    float4 v0 = *(const float4*)(Vc + ((size_t)b * 256 + e) * 8);
    float4 v1 = *(const float4*)(Vc + ((size_t)b * 256 + e) * 8 + 4);
    Vl[e][0] = v0.x; Vl[e][1] = v0.y; Vl[e][2] = v0.z; Vl[e][3] = v0.w;
    Vl[e][4] = v1.x; Vl[e][5] = v1.y; Vl[e][6] = v1.z; Vl[e][7] = v1.w;
    if (e < 8) wr[e] = Wrow[((size_t)b * 256 + dd) * 8 + e];
    __syncthreads();
    if (e >= dd) {
        float v = (e == dd) ? s0[b] : 0.f;
        #pragma unroll
        for (int j = 0; j < 8; ++j) v += wr[j] * Vl[e][j];
        size_t idx = (size_t)b * 32896 + (size_t)dd * 256 - ((size_t)dd * (dd - 1)) / 2 + (e - dd);
        out[idx] = v;
    }
}

extern "C" void kernel_launch(void* const* d_in, const int* in_sizes, int n_in,
                              void* d_out, int out_size, void* d_ws, size_t ws_size,
                              hipStream_t stream) {
    const float* x    = (const float*)d_in[0];
    const float* cent = (const float*)d_in[1];
    const float* Winp = (const float*)d_in[2];
    const float* binp = (const float*)d_in[3];
    const float* Wg   = (const float*)d_in[4];
    const float* bg   = (const float*)d_in[5];
    const float* Wgk  = (const float*)d_in[6];
    const float* Wf   = (const float*)d_in[8];
    const float* bf   = (const float*)d_in[9];
    float* out = (float*)d_out;
    char* wsb = (char*)d_ws;

    // byte-offset workspace layout
    float* lt    = (float*)(wsb);                        // [4][1024][1024] f32, 16 MB
    u16*   xtnb  = (u16*)(wsb);                          // alias (dead before lt written), 8 MB
    u16*   hb    = (u16*)(wsb + (16ull << 20));          // [4096][2048] bf16, 16 MB
    u16*   winpb = (u16*)(wsb + (32ull << 20));          // [2048][1024] bf16, 4 MB
    u16*   wgkb  = (u16*)(wsb + (36ull << 20));          // [1024][2048] bf16, 4 MB
    float* agT   = (float*)(wsb + (40ull << 20));
    float* wsum  = agT + 32768;
    float* wf    = wsum + 4096;
    float* u     = wf + 32768;
    float* vfp   = u + 4096;
    float* Vc    = vfp + 32768;
    float* Wr    = Vc + 8192;
    float* s0    = Wr + 8192;

    k_transpose_norm<<<dim3(32, 16), 256, 0, stream>>>(x, xtnb);
    k_f2bf<<<2048, 256, 0, stream>>>(Winp, winpb, 2097152);
    k_f2bf<<<2048, 256, 0, stream>>>(Wgk, wgkb, 2097152);
    // GEMM1: h[bm,j] = xtn @ W_inp^T + b_inp -> bf16  (M=4096, N=2048, K=1024)
    k_mfma_gemm<1><<<dim3(16, 32, 1), 256, 0, stream>>>(
        xtnb, winpb, nullptr, hb, binp, 1024, 2048, 0, 0);
    k_alpha_g<<<4096, 64, 0, stream>>>(hb, Wg, bg, agT);
    // GEMM2: logitsT[b][gk][m] = W_gk @ h_b^T -> f32  (M=1024, N=1024, K=2048, z=4)
    // (bias omitted: softmax over m is shift-invariant)
    k_mfma_gemm<0><<<dim3(8, 8, 4), 256, 0, stream>>>(
        wgkb, hb, lt, nullptr, nullptr, 2048, 1024, 2097152LL, 1048576LL);
    k_softmax<<<dim3(1024, 4), 256, 0, stream>>>(lt, agT, wsum);
    k_wf_u<<<32, 256, 0, stream>>>(lt, wsum, Wf, wf, u);
    k_vf_partial<<<dim3(4, 8, 4), 256, 0, stream>>>(hb, wf, vfp);
    k_finalize<<<4, 256, 0, stream>>>(vfp, u, cent, bf, Vc, Wr, s0);
    k_output<<<dim3(256, 4), 256, 0, stream>>>(Vc, Wr, s0, out);
}

// Round 3
// 177.643 us; speedup vs baseline: 3.2196x; 1.0009x over previous
//
#include <hip/hip_runtime.h>
#include <math.h>

typedef float f32x4 __attribute__((ext_vector_type(4)));
typedef short bf16x8 __attribute__((ext_vector_type(8)));
typedef unsigned short u16;

__device__ __forceinline__ u16 f2bf(float f) {
    unsigned u = __builtin_bit_cast(unsigned, f);
    u += 0x7fff + ((u >> 16) & 1);   // RNE
    return (u16)(u >> 16);
}
__device__ __forceinline__ float bf2f(u16 s) {
    unsigned v = ((unsigned)s) << 16;
    return __builtin_bit_cast(float, v);
}
__device__ __forceinline__ void gload16(const void* g, void* l) {
    __builtin_amdgcn_global_load_lds(
        (const __attribute__((address_space(1))) unsigned int*)g,
        (__attribute__((address_space(3))) unsigned int*)l, 16, 0, 0);
}

// ---------------- K0: f32 -> bf16 convert ----------------
__global__ __launch_bounds__(256) void k_f2bf(const float* __restrict__ in,
                                              u16* __restrict__ out, int n) {
    int i = (blockIdx.x * 256 + threadIdx.x) * 4;
    if (i < n) {
        float4 v = *(const float4*)(in + i);
        ushort4 o;
        o.x = f2bf(v.x); o.y = f2bf(v.y); o.z = f2bf(v.z); o.w = f2bf(v.w);
        *(ushort4*)(out + i) = o;
    }
}

// ---------------- K1: transpose + L2 normalize -> bf16 ----------------
// x [32,1024,16,8] -> xtn[b][m][c] bf16, m = t*128 + h*8 + w, row L2-normalized over c
__global__ __launch_bounds__(256) void k_transpose_norm(const float* __restrict__ x,
                                                        u16* __restrict__ xtn) {
    int b8 = blockIdx.x;   // 0..31
    int hh = blockIdx.y;   // 0..15
    int tid = threadIdx.x; // 256
    __shared__ float tile[8][1032];
    __shared__ float inv[8];
    const float* src = x + (size_t)b8 * 1024 * 128 + hh * 8;
    #pragma unroll
    for (int r = 0; r < 4; ++r) {
        int c = tid * 4 + r;
        const float* p = src + (size_t)c * 128;
        float4 v0 = *(const float4*)(p);
        float4 v1 = *(const float4*)(p + 4);
        tile[0][c] = v0.x; tile[1][c] = v0.y; tile[2][c] = v0.z; tile[3][c] = v0.w;
        tile[4][c] = v1.x; tile[5][c] = v1.y; tile[6][c] = v1.z; tile[7][c] = v1.w;
    }
    __syncthreads();
    int w = tid >> 5, j = tid & 31;
    float s = 0.f;
    #pragma unroll 8
    for (int i = 0; i < 32; ++i) { float v = tile[w][i * 32 + j]; s += v * v; }
    #pragma unroll
    for (int m = 16; m; m >>= 1) s += __shfl_xor(s, m);
    if (j == 0) inv[w] = 1.0f / fmaxf(sqrtf(s), 1e-12f);
    __syncthreads();
    int b = b8 >> 3, t = b8 & 7;
    int c0 = tid * 4;
    for (int w2 = 0; w2 < 8; ++w2) {
        int m = t * 128 + hh * 8 + w2;
        float sc = inv[w2];
        u16* dst = xtn + ((size_t)b * 1024 + m) * 1024;
        ushort4 o;
        o.x = f2bf(tile[w2][c0 + 0] * sc);
        o.y = f2bf(tile[w2][c0 + 1] * sc);
        o.z = f2bf(tile[w2][c0 + 2] * sc);
        o.w = f2bf(tile[w2][c0 + 3] * sc);
        *(ushort4*)(dst + c0) = o;
    }
}

// ---------------- K2: bf16 MFMA GEMM (BT): C[i,j] = sum_k A[i,k]*B[j,k] ----------------
// 128x128 tile, 4 waves 2x2 (64x64 each), K_STEP=32, mfma_f32_16x16x32_bf16.
// MODE 0: f32 out, no bias.  MODE 1: bf16 out + column bias.
template <int MODE>
__global__ __launch_bounds__(256) void k_mfma_gemm(
    const u16* __restrict__ A, const u16* __restrict__ B,
    float* __restrict__ Cf, u16* __restrict__ Cb,
    const float* __restrict__ bias, int K, int N,
    long long Bstr, long long Cstr)
{
    int bz = blockIdx.z;
    B += (size_t)bz * Bstr;
    int tid = threadIdx.x, lane = tid & 63, wave = tid >> 6;
    int wr = wave >> 1, wc = wave & 1;
    int i0 = blockIdx.y * 128, j0 = blockIdx.x * 128;
    __shared__ u16 As[2][128 * 32];
    __shared__ u16 Bs[2][128 * 32];
    f32x4 acc[4][4] = {};
    int lrow = lane >> 2, lk = (lane & 3) * 8;
    int fr = lane & 15, fg = lane >> 4;

    auto stage = [&](int buf, int kt) {
        #pragma unroll
        for (int q = 0; q < 2; ++q) {
            int blk = q * 4 + wave;  // 16-row block of the 128-row tile
            gload16(A + (size_t)(i0 + blk * 16 + lrow) * K + kt + lk, &As[buf][blk * 512]);
            gload16(B + (size_t)(j0 + blk * 16 + lrow) * K + kt + lk, &Bs[buf][blk * 512]);
        }
    };
    auto compute = [&](int buf) {
        bf16x8 af[4], bv[4];
        #pragma unroll
        for (int mi = 0; mi < 4; ++mi)
            af[mi] = *(const bf16x8*)&As[buf][(wr * 64 + mi * 16 + fr) * 32 + fg * 8];
        #pragma unroll
        for (int ni = 0; ni < 4; ++ni)
            bv[ni] = *(const bf16x8*)&Bs[buf][(wc * 64 + ni * 16 + fr) * 32 + fg * 8];
        #pragma unroll
        for (int mi = 0; mi < 4; ++mi)
            #pragma unroll
            for (int ni = 0; ni < 4; ++ni)
                acc[mi][ni] = __builtin_amdgcn_mfma_f32_16x16x32_bf16(
                    af[mi], bv[ni], acc[mi][ni], 0, 0, 0);
    };

    stage(0, 0);
    __syncthreads();
    int nk = K >> 5, cur = 0;
    for (int t = 0; t < nk - 1; ++t) {
        stage(cur ^ 1, (t + 1) << 5);  // prefetch next tile (in flight under MFMA)
        compute(cur);
        __syncthreads();               // vmcnt(0)+barrier: next tile ready, cur reusable
        cur ^= 1;
    }
    compute(cur);

    // epilogue: C/D layout col = lane&15, row = (lane>>4)*4 + r  [m89]
    if (MODE == 1) {
        #pragma unroll
        for (int ni = 0; ni < 4; ++ni) {
            int col = j0 + wc * 64 + ni * 16 + fr;
            float bvv = bias[col];
            #pragma unroll
            for (int mi = 0; mi < 4; ++mi)
                #pragma unroll
                for (int r = 0; r < 4; ++r) {
                    int row = i0 + wr * 64 + mi * 16 + fg * 4 + r;
                    Cb[(size_t)row * N + col] = f2bf(acc[mi][ni][r] + bvv);
                }
        }
    } else {
        float* C2 = Cf + (size_t)bz * Cstr;
        #pragma unroll
        for (int ni = 0; ni < 4; ++ni) {
            int col = j0 + wc * 64 + ni * 16 + fr;
            #pragma unroll
            for (int mi = 0; mi < 4; ++mi)
                #pragma unroll
                for (int r = 0; r < 4; ++r) {
                    int row = i0 + wr * 64 + mi * 16 + fg * 4 + r;
                    C2[(size_t)row * N + col] = acc[mi][ni][r];
                }
        }
    }
}

// ---------------- K3: alpha_g = sigmoid(h @ W_g^T + b_g), stored transposed [b][g][m] ----------------
__global__ void k_alpha_g(const u16* __restrict__ h, const float* __restrict__ Wg,
                          const float* __restrict__ bg, float* __restrict__ agT) {
    int bm = blockIdx.x;     // 0..4095
    int lane = threadIdx.x;  // 64
    const u16* hr = h + (size_t)bm * 2048;
    float acc[8] = {};
    for (int c = lane; c < 2048; c += 64) {
        float hv = bf2f(hr[c]);
        #pragma unroll
        for (int g = 0; g < 8; ++g) acc[g] += hv * Wg[g * 2048 + c];
    }
    int b = bm >> 10, m = bm & 1023;
    #pragma unroll
    for (int g = 0; g < 8; ++g) {
        float tot = acc[g];
        #pragma unroll
        for (int mm = 32; mm; mm >>= 1) tot += __shfl_xor(tot, mm);
        if (lane == g) {
            float v = tot + bg[g];
            agT[((size_t)b * 8 + g) * 1024 + m] = 1.f / (1.f + expf(-v));
        }
    }
}

// ---------------- K4: softmax over m (row of logitsT), * alpha_g, in-place; wsum ----------------
__global__ __launch_bounds__(256) void k_softmax(float* __restrict__ lt,
                                                 const float* __restrict__ agT,
                                                 float* __restrict__ wsum) {
    int gk = blockIdx.x, b = blockIdx.y;
    int tid = threadIdx.x;
    float* row = lt + ((size_t)b * 1024 + gk) * 1024;
    int g = gk >> 7;
    const float* ag = agT + ((size_t)b * 8 + g) * 1024;
    __shared__ float red[4], red2[4], red3[4];
    float4 v = *(const float4*)(row + tid * 4);
    float mx = fmaxf(fmaxf(v.x, v.y), fmaxf(v.z, v.w));
    #pragma unroll
    for (int m = 32; m; m >>= 1) mx = fmaxf(mx, __shfl_xor(mx, m));
    if ((tid & 63) == 0) red[tid >> 6] = mx;
    __syncthreads();
    mx = fmaxf(fmaxf(red[0], red[1]), fmaxf(red[2], red[3]));
    float e0 = expf(v.x - mx), e1 = expf(v.y - mx), e2 = expf(v.z - mx), e3 = expf(v.w - mx);
    float s = e0 + e1 + e2 + e3;
    #pragma unroll
    for (int m = 32; m; m >>= 1) s += __shfl_xor(s, m);
    if ((tid & 63) == 0) red2[tid >> 6] = s;
    __syncthreads();
    s = red2[0] + red2[1] + red2[2] + red2[3];
    float invs = 1.f / s;
    float4 a = *(const float4*)(ag + tid * 4);
    float w0 = e0 * invs * a.x, w1 = e1 * invs * a.y, w2 = e2 * invs * a.z, w3 = e3 * invs * a.w;
    float4 o; o.x = w0; o.y = w1; o.z = w2; o.w = w3;
    *(float4*)(row + tid * 4) = o;
    float t = w0 + w1 + w2 + w3;
    #pragma unroll
    for (int m = 32; m; m >>= 1) t += __shfl_xor(t, m);
    if ((tid & 63) == 0) red3[tid >> 6] = t;
    __syncthreads();
    if (tid == 0) wsum[((size_t)b * 8 + g) * 128 + (gk & 127)] = red3[0] + red3[1] + red3[2] + red3[3];
}

// ---------------- K4b: wf[b,g,m] = sum_k Wf[k]*w[b,gk,m];  u = Wf*wsum ----------------
__global__ __launch_bounds__(256) void k_wf_u(const float* __restrict__ wT,
                                              const float* __restrict__ wsum,
                                              const float* __restrict__ Wf,
                                              float* __restrict__ wf, float* __restrict__ u) {
    int bg = blockIdx.x;  // 0..31
    int tid = threadIdx.x;
    __shared__ float wfl[128];
    if (tid < 128) {
        wfl[tid] = Wf[tid];
        u[bg * 128 + tid] = Wf[tid] * wsum[bg * 128 + tid];
    }
    __syncthreads();
    const float* base = wT + (size_t)bg * 128 * 1024;
    float acc[4] = {};
    for (int k = 0; k < 128; ++k) {
        float wfk = wfl[k];
        const float* r = base + (size_t)k * 1024;
        #pragma unroll
        for (int q = 0; q < 4; ++q) acc[q] += wfk * r[tid + q * 256];
    }
    #pragma unroll
    for (int q = 0; q < 4; ++q) wf[(size_t)bg * 1024 + tid + q * 256] = acc[q];
}

// ---------------- K5: vf partial = sum_{m in chunk} wf[m]*h[b,m,g*256+d] ----------------
__global__ __launch_bounds__(256) void k_vf_partial(const u16* __restrict__ h,
                                                    const float* __restrict__ wf,
                                                    float* __restrict__ vfp) {
    int mc = blockIdx.x, g = blockIdx.y, b = blockIdx.z;
    int d = threadIdx.x;
    __shared__ float wl[256];
    wl[d] = wf[((size_t)b * 8 + g) * 1024 + mc * 256 + d];
    __syncthreads();
    const u16* hb = h + (size_t)b * 1024 * 2048 + (size_t)(mc * 256) * 2048 + g * 256;
    float acc = 0.f;
    #pragma unroll 8
    for (int m = 0; m < 256; ++m) acc += wl[m] * bf2f(hb[(size_t)m * 2048 + d]);
    vfp[(((size_t)(b * 8 + g)) * 4 + mc) * 256 + d] = acc;
}

// ---------------- K6: finalize vf, center, trace, S(8x8), rank-8 Newton-Schulz ----------------
#define MM8(DST, P, Q) do { if (act) { float s_ = 0.f; \
    _Pragma("unroll") \
    for (int l_ = 0; l_ < 8; ++l_) s_ += P[ii][l_] * Q[l_][jj]; \
    DST[ii][jj] = s_; } __syncthreads(); } while (0)

__global__ __launch_bounds__(256) void k_finalize(const float* __restrict__ vfp,
                                                  const float* __restrict__ u,
                                                  const float* __restrict__ cent,
                                                  const float* __restrict__ bf,
                                                  float* __restrict__ VcOut,
                                                  float* __restrict__ Wrow,
                                                  float* __restrict__ s0) {
    int b = blockIdx.x;
    int tid = threadIdx.x;  // 256
    __shared__ float ul[8][128];
    __shared__ float Vl[256][9];
    __shared__ float red[256];
    __shared__ float Sm[8][8], W1[8][8], W2[8][8], YmL[8][8], ZmL[8][8], ZYL[8][8], FmL[8][8];
    for (int i = tid; i < 1024; i += 256) ul[i >> 7][i & 127] = u[b * 1024 + i];
    __syncthreads();
    int d = tid;
    float bfv = bf[0];
    float vfl[8];
    #pragma unroll
    for (int g = 0; g < 8; ++g) {
        float acc = 0.f;
        #pragma unroll
        for (int mc = 0; mc < 4; ++mc) acc += vfp[(((size_t)(b * 8 + g)) * 4 + mc) * 256 + d];
        float ct = 0.f;
        for (int k = 0; k < 128; ++k) ct += ul[g][k] * cent[k * 256 + d];
        vfl[g] = acc - ct + bfv;
    }
    float mean = 0.f;
    #pragma unroll
    for (int g = 0; g < 8; ++g) mean += vfl[g];
    mean *= 0.125f;
    float trp = 0.f;
    #pragma unroll
    for (int g = 0; g < 8; ++g) { float v = vfl[g] - mean; Vl[d][g] = v; trp += v * v; }
    red[tid] = trp;
    __syncthreads();
    for (int s = 128; s > 0; s >>= 1) { if (tid < s) red[tid] += red[tid + s]; __syncthreads(); }
    float tr = red[0] * 0.125f;  // trace(cov)
    bool act = tid < 64;
    int ii = (tid >> 3) & 7, jj = tid & 7;
    if (act) {
        float sv = 0.f;
        for (int dd = 0; dd < 256; ++dd) sv += Vl[dd][ii] * Vl[dd][jj];
        Sm[ii][jj] = sv / (8.f * tr);
    }
    __syncthreads();
    // representation: mat = a*I + U B U^T, S = U^T U; product (a,P)(c,Q)=(ac, aQ+cP+P S Q)
    if (act) {
        YmL[ii][jj] = (ii == jj ? 1.5f : 0.f) - 0.5f * Sm[ii][jj];
        ZmL[ii][jj] = (ii == jj ? -0.5f : 0.f);
    }
    __syncthreads();
    float ya = 0.f, za = 1.5f;
    MM8(W1, Sm, YmL);
    MM8(W2, ZmL, W1);
    float pa = za * ya;
    if (act) ZYL[ii][jj] = -0.5f * (za * YmL[ii][jj] + ya * ZmL[ii][jj] + W2[ii][jj]);
    __syncthreads();
    float zya = 1.5f - 0.5f * pa;
    MM8(W1, Sm, ZYL);
    MM8(W2, YmL, W1);
    if (act) YmL[ii][jj] = ya * ZYL[ii][jj] + zya * YmL[ii][jj] + W2[ii][jj];
    __syncthreads();
    ya = ya * zya;
    MM8(W1, Sm, ZmL);
    MM8(W2, ZYL, W1);
    if (act) ZmL[ii][jj] = zya * ZmL[ii][jj] + za * ZYL[ii][jj] + W2[ii][jj];
    __syncthreads();
    za = zya * za;
    MM8(W1, Sm, YmL);
    MM8(W2, ZmL, W1);
    float p2a = za * ya;
    if (act) ZYL[ii][jj] = za * YmL[ii][jj] + ya * ZmL[ii][jj] + W2[ii][jj];
    __syncthreads();
    MM8(W1, Sm, ZYL);
    MM8(W2, YmL, W1);
    if (act) FmL[ii][jj] = 0.5f * ((3.f - p2a) * YmL[ii][jj] - ya * ZYL[ii][jj] - W2[ii][jj]);
    __syncthreads();
    float fa = 0.5f * ya * (3.f - p2a);
    float sqtr = sqrtf(tr);
    float scaleF = 1.f / (8.f * sqtr);
    #pragma unroll
    for (int jo = 0; jo < 8; ++jo) {
        float sv = 0.f;
        #pragma unroll
        for (int i = 0; i < 8; ++i) sv += Vl[d][i] * FmL[i][jo];
        Wrow[((size_t)b * 256 + d) * 8 + jo] = sv * scaleF;
    }
    #pragma unroll
    for (int jo = 0; jo < 8; ++jo) VcOut[((size_t)b * 256 + d) * 8 + jo] = Vl[d][jo];
    if (tid == 0) s0[b] = fa * sqtr;
}

// ---------------- K7: triuvec output: R[d,e] = s0*delta + Wrow[d,:].Vc[e,:] ----------------
__global__ __launch_bounds__(256) void k_output(const float* __restrict__ Vc,
                                                const float* __restrict__ Wrow,
                                                const float* __restrict__ s0,
                                                float* __restrict__ out) {
    int dd = blockIdx.x, b = blockIdx.y;
    int e = threadIdx.x;
    __shared__ float Vl[256][9];
    __shared__ float wr[8];
    float4 v0 = *(const float4*)(Vc + ((size_t)b * 256 + e) * 8);
    float4 v1 = *(const float4*)(Vc + ((size_t)b * 256 + e) * 8 + 4);
    Vl[e][0] = v0.x; Vl[e][1] = v0.y; Vl[e][2] = v0.z; Vl[e][3] = v0.w;
    Vl[e][4] = v1.x; Vl[e][5] = v1.y; Vl[e][6] = v1.z; Vl[e][7] = v1.w;
    if (e < 8) wr[e] = Wrow[((size_t)b * 256 + dd) * 8 + e];
    __syncthreads();
    if (e >= dd) {
        float v = (e == dd) ? s0[b] : 0.f;
        #pragma unroll
        for (int j = 0; j < 8; ++j) v += wr[j] * Vl[e][j];
        size_t idx = (size_t)b * 32896 + (size_t)dd * 256 - ((size_t)dd * (dd - 1)) / 2 + (e - dd);
        out[idx] = v;
    }
}

extern "C" void kernel_launch(void* const* d_in, const int* in_sizes, int n_in,
                              void* d_out, int out_size, void* d_ws, size_t ws_size,
                              hipStream_t stream) {
    const float* x    = (const float*)d_in[0];
    const float* cent = (const float*)d_in[1];
    const float* Winp = (const float*)d_in[2];
    const float* binp = (const float*)d_in[3];
    const float* Wg   = (const float*)d_in[4];
    const float* bg   = (const float*)d_in[5];
    const float* Wgk  = (const float*)d_in[6];
    const float* Wf   = (const float*)d_in[8];
    const float* bf   = (const float*)d_in[9];
    float* out = (float*)d_out;
    char* wsb = (char*)d_ws;

    // byte-offset workspace layout
    float* lt    = (float*)(wsb);                        // [4][1024][1024] f32, 16 MB
    u16*   xtnb  = (u16*)(wsb);                          // alias (dead before lt written), 8 MB
    u16*   hb    = (u16*)(wsb + (16ull << 20));          // [4096][2048] bf16, 16 MB
    u16*   winpb = (u16*)(wsb + (32ull << 20));          // [2048][1024] bf16, 4 MB
    u16*   wgkb  = (u16*)(wsb + (36ull << 20));          // [1024][2048] bf16, 4 MB
    float* agT   = (float*)(wsb + (40ull << 20));
    float* wsum  = agT + 32768;
    float* wf    = wsum + 4096;
    float* u     = wf + 32768;
    float* vfp   = u + 4096;
    float* Vc    = vfp + 32768;
    float* Wr    = Vc + 8192;
    float* s0    = Wr + 8192;

    k_transpose_norm<<<dim3(32, 16), 256, 0, stream>>>(x, xtnb);
    k_f2bf<<<2048, 256, 0, stream>>>(Winp, winpb, 2097152);
    k_f2bf<<<2048, 256, 0, stream>>>(Wgk, wgkb, 2097152);
    // GEMM1: h[bm,j] = xtn @ W_inp^T + b_inp -> bf16  (M=4096, N=2048, K=1024)
    k_mfma_gemm<1><<<dim3(16, 32, 1), 256, 0, stream>>>(
        xtnb, winpb, nullptr, hb, binp, 1024, 2048, 0, 0);
    k_alpha_g<<<4096, 64, 0, stream>>>(hb, Wg, bg, agT);
    // GEMM2: logitsT[b][gk][m] = W_gk @ h_b^T -> f32  (M=1024, N=1024, K=2048, z=4)
    // (bias omitted: softmax over m is shift-invariant)
    k_mfma_gemm<0><<<dim3(8, 8, 4), 256, 0, stream>>>(
        wgkb, hb, lt, nullptr, nullptr, 2048, 1024, 2097152LL, 1048576LL);
    k_softmax<<<dim3(1024, 4), 256, 0, stream>>>(lt, agT, wsum);
    k_wf_u<<<32, 256, 0, stream>>>(lt, wsum, Wf, wf, u);
    k_vf_partial<<<dim3(4, 8, 4), 256, 0, stream>>>(hb, wf, vfp);
    k_finalize<<<4, 256, 0, stream>>>(vfp, u, cent, bf, Vc, Wr, s0);
    k_output<<<dim3(256, 4), 256, 0, stream>>>(Vc, Wr, s0, out);
}

// Round 4
// 177.339 us; speedup vs baseline: 3.2251x; 1.0017x over previous
//
#include <hip/hip_runtime.h>
#include <math.h>

typedef float f32x4 __attribute__((ext_vector_type(4)));
typedef short bf16x8 __attribute__((ext_vector_type(8)));
typedef unsigned short u16;

__device__ __forceinline__ u16 f2bf(float f) {
    unsigned u = __builtin_bit_cast(unsigned, f);
    u += 0x7fff + ((u >> 16) & 1);   // RNE
    return (u16)(u >> 16);
}
__device__ __forceinline__ float bf2f(u16 s) {
    unsigned v = ((unsigned)s) << 16;
    return __builtin_bit_cast(float, v);
}
__device__ __forceinline__ void gload16(const void* g, void* l) {
    __builtin_amdgcn_global_load_lds(
        (const __attribute__((address_space(1))) unsigned int*)g,
        (__attribute__((address_space(3))) unsigned int*)l, 16, 0, 0);
}

// ---------------- K0: f32 -> bf16 convert ----------------
__global__ __launch_bounds__(256) void k_f2bf(const float* __restrict__ in,
                                              u16* __restrict__ out, int n) {
    int i = (blockIdx.x * 256 + threadIdx.x) * 4;
    if (i < n) {
        float4 v = *(const float4*)(in + i);
        ushort4 o;
        o.x = f2bf(v.x); o.y = f2bf(v.y); o.z = f2bf(v.z); o.w = f2bf(v.w);
        *(ushort4*)(out + i) = o;
    }
}

// ---------------- K1: transpose + L2 normalize -> bf16 ----------------
// x [32,1024,16,8] -> xtn[b][m][c] bf16, m = t*128 + h*8 + w, row L2-normalized over c
__global__ __launch_bounds__(256) void k_transpose_norm(const float* __restrict__ x,
                                                        u16* __restrict__ xtn) {
    int b8 = blockIdx.x;   // 0..31
    int hh = blockIdx.y;   // 0..15
    int tid = threadIdx.x; // 256
    __shared__ float tile[8][1032];
    __shared__ float inv[8];
    const float* src = x + (size_t)b8 * 1024 * 128 + hh * 8;
    #pragma unroll
    for (int r = 0; r < 4; ++r) {
        int c = tid * 4 + r;
        const float* p = src + (size_t)c * 128;
        float4 v0 = *(const float4*)(p);
        float4 v1 = *(const float4*)(p + 4);
        tile[0][c] = v0.x; tile[1][c] = v0.y; tile[2][c] = v0.z; tile[3][c] = v0.w;
        tile[4][c] = v1.x; tile[5][c] = v1.y; tile[6][c] = v1.z; tile[7][c] = v1.w;
    }
    __syncthreads();
    int w = tid >> 5, j = tid & 31;
    float s = 0.f;
    #pragma unroll 8
    for (int i = 0; i < 32; ++i) { float v = tile[w][i * 32 + j]; s += v * v; }
    #pragma unroll
    for (int m = 16; m; m >>= 1) s += __shfl_xor(s, m);
    if (j == 0) inv[w] = 1.0f / fmaxf(sqrtf(s), 1e-12f);
    __syncthreads();
    int b = b8 >> 3, t = b8 & 7;
    int c0 = tid * 4;
    for (int w2 = 0; w2 < 8; ++w2) {
        int m = t * 128 + hh * 8 + w2;
        float sc = inv[w2];
        u16* dst = xtn + ((size_t)b * 1024 + m) * 1024;
        ushort4 o;
        o.x = f2bf(tile[w2][c0 + 0] * sc);
        o.y = f2bf(tile[w2][c0 + 1] * sc);
        o.z = f2bf(tile[w2][c0 + 2] * sc);
        o.w = f2bf(tile[w2][c0 + 3] * sc);
        *(ushort4*)(dst + c0) = o;
    }
}

// ---------------- K2: bf16 MFMA GEMM (BT): C[i,j] = sum_k A[i,k]*B[j,k] ----------------
// 128x128 tile, 4 waves 2x2 (64x64 each), K_STEP=32, mfma_f32_16x16x32_bf16.
// MODE 0: f32 out, no bias.  MODE 1: bf16 out + column bias.
template <int MODE>
__global__ __launch_bounds__(256) void k_mfma_gemm(
    const u16* __restrict__ A, const u16* __restrict__ B,
    float* __restrict__ Cf, u16* __restrict__ Cb,
    const float* __restrict__ bias, int K, int N,
    long long Bstr, long long Cstr)
{
    int bz = blockIdx.z;
    B += (size_t)bz * Bstr;
    int tid = threadIdx.x, lane = tid & 63, wave = tid >> 6;
    int wr = wave >> 1, wc = wave & 1;
    int i0 = blockIdx.y * 128, j0 = blockIdx.x * 128;
    __shared__ u16 As[2][128 * 32];
    __shared__ u16 Bs[2][128 * 32];
    f32x4 acc[4][4] = {};
    int lrow = lane >> 2, lk = (lane & 3) * 8;
    int fr = lane & 15, fg = lane >> 4;

    auto stage = [&](int buf, int kt) {
        #pragma unroll
        for (int q = 0; q < 2; ++q) {
            int blk = q * 4 + wave;  // 16-row block of the 128-row tile
            gload16(A + (size_t)(i0 + blk * 16 + lrow) * K + kt + lk, &As[buf][blk * 512]);
            gload16(B + (size_t)(j0 + blk * 16 + lrow) * K + kt + lk, &Bs[buf][blk * 512]);
        }
    };
    auto compute = [&](int buf) {
        bf16x8 af[4], bv[4];
        #pragma unroll
        for (int mi = 0; mi < 4; ++mi)
            af[mi] = *(const bf16x8*)&As[buf][(wr * 64 + mi * 16 + fr) * 32 + fg * 8];
        #pragma unroll
        for (int ni = 0; ni < 4; ++ni)
            bv[ni] = *(const bf16x8*)&Bs[buf][(wc * 64 + ni * 16 + fr) * 32 + fg * 8];
        #pragma unroll
        for (int mi = 0; mi < 4; ++mi)
            #pragma unroll
            for (int ni = 0; ni < 4; ++ni)
                acc[mi][ni] = __builtin_amdgcn_mfma_f32_16x16x32_bf16(
                    af[mi], bv[ni], acc[mi][ni], 0, 0, 0);
    };

    stage(0, 0);
    __syncthreads();
    int nk = K >> 5, cur = 0;
    for (int t = 0; t < nk - 1; ++t) {
        stage(cur ^ 1, (t + 1) << 5);  // prefetch next tile (in flight under MFMA)
        compute(cur);
        __syncthreads();               // vmcnt(0)+barrier: next tile ready, cur reusable
        cur ^= 1;
    }
    compute(cur);

    // epilogue: C/D layout col = lane&15, row = (lane>>4)*4 + r  [m89]
    if (MODE == 1) {
        #pragma unroll
        for (int ni = 0; ni < 4; ++ni) {
            int col = j0 + wc * 64 + ni * 16 + fr;
            float bvv = bias[col];
            #pragma unroll
            for (int mi = 0; mi < 4; ++mi)
                #pragma unroll
                for (int r = 0; r < 4; ++r) {
                    int row = i0 + wr * 64 + mi * 16 + fg * 4 + r;
                    Cb[(size_t)row * N + col] = f2bf(acc[mi][ni][r] + bvv);
                }
        }
    } else {
        float* C2 = Cf + (size_t)bz * Cstr;
        #pragma unroll
        for (int ni = 0; ni < 4; ++ni) {
            int col = j0 + wc * 64 + ni * 16 + fr;
            #pragma unroll
            for (int mi = 0; mi < 4; ++mi)
                #pragma unroll
                for (int r = 0; r < 4; ++r) {
                    int row = i0 + wr * 64 + mi * 16 + fg * 4 + r;
                    C2[(size_t)row * N + col] = acc[mi][ni][r];
                }
        }
    }
}

// ---------------- K3: alpha_g = sigmoid(h @ W_g^T + b_g), stored transposed [b][g][m] ----------------
__global__ void k_alpha_g(const u16* __restrict__ h, const float* __restrict__ Wg,
                          const float* __restrict__ bg, float* __restrict__ agT) {
    int bm = blockIdx.x;     // 0..4095
    int lane = threadIdx.x;  // 64
    const u16* hr = h + (size_t)bm * 2048;
    float acc[8] = {};
    for (int c = lane; c < 2048; c += 64) {
        float hv = bf2f(hr[c]);
        #pragma unroll
        for (int g = 0; g < 8; ++g) acc[g] += hv * Wg[g * 2048 + c];
    }
    int b = bm >> 10, m = bm & 1023;
    #pragma unroll
    for (int g = 0; g < 8; ++g) {
        float tot = acc[g];
        #pragma unroll
        for (int mm = 32; mm; mm >>= 1) tot += __shfl_xor(tot, mm);
        if (lane == g) {
            float v = tot + bg[g];
            agT[((size_t)b * 8 + g) * 1024 + m] = 1.f / (1.f + expf(-v));
        }
    }
}

// ---------------- K4: softmax over m (row of logitsT), * alpha_g, in-place; wsum ----------------
__global__ __launch_bounds__(256) void k_softmax(float* __restrict__ lt,
                                                 const float* __restrict__ agT,
                                                 float* __restrict__ wsum) {
    int gk = blockIdx.x, b = blockIdx.y;
    int tid = threadIdx.x;
    float* row = lt + ((size_t)b * 1024 + gk) * 1024;
    int g = gk >> 7;
    const float* ag = agT + ((size_t)b * 8 + g) * 1024;
    __shared__ float red[4], red2[4], red3[4];
    float4 v = *(const float4*)(row + tid * 4);
    float mx = fmaxf(fmaxf(v.x, v.y), fmaxf(v.z, v.w));
    #pragma unroll
    for (int m = 32; m; m >>= 1) mx = fmaxf(mx, __shfl_xor(mx, m));
    if ((tid & 63) == 0) red[tid >> 6] = mx;
    __syncthreads();
    mx = fmaxf(fmaxf(red[0], red[1]), fmaxf(red[2], red[3]));
    float e0 = expf(v.x - mx), e1 = expf(v.y - mx), e2 = expf(v.z - mx), e3 = expf(v.w - mx);
    float s = e0 + e1 + e2 + e3;
    #pragma unroll
    for (int m = 32; m; m >>= 1) s += __shfl_xor(s, m);
    if ((tid & 63) == 0) red2[tid >> 6] = s;
    __syncthreads();
    s = red2[0] + red2[1] + red2[2] + red2[3];
    float invs = 1.f / s;
    float4 a = *(const float4*)(ag + tid * 4);
    float w0 = e0 * invs * a.x, w1 = e1 * invs * a.y, w2 = e2 * invs * a.z, w3 = e3 * invs * a.w;
    float4 o; o.x = w0; o.y = w1; o.z = w2; o.w = w3;
    *(float4*)(row + tid * 4) = o;
    float t = w0 + w1 + w2 + w3;
    #pragma unroll
    for (int m = 32; m; m >>= 1) t += __shfl_xor(t, m);
    if ((tid & 63) == 0) red3[tid >> 6] = t;
    __syncthreads();
    if (tid == 0) wsum[((size_t)b * 8 + g) * 128 + (gk & 127)] = red3[0] + red3[1] + red3[2] + red3[3];
}

// ---------------- K4b: wf[b,g,m] = sum_k Wf[k]*w[b,gk,m];  u = Wf*wsum ----------------
__global__ __launch_bounds__(256) void k_wf_u(const float* __restrict__ wT,
                                              const float* __restrict__ wsum,
                                              const float* __restrict__ Wf,
                                              float* __restrict__ wf, float* __restrict__ u) {
    int bg = blockIdx.x;  // 0..31
    int tid = threadIdx.x;
    __shared__ float wfl[128];
    if (tid < 128) {
        wfl[tid] = Wf[tid];
        u[bg * 128 + tid] = Wf[tid] * wsum[bg * 128 + tid];
    }
    __syncthreads();
    const float* base = wT + (size_t)bg * 128 * 1024;
    float acc[4] = {};
    for (int k = 0; k < 128; ++k) {
        float wfk = wfl[k];
        const float* r = base + (size_t)k * 1024;
        #pragma unroll
        for (int q = 0; q < 4; ++q) acc[q] += wfk * r[tid + q * 256];
    }
    #pragma unroll
    for (int q = 0; q < 4; ++q) wf[(size_t)bg * 1024 + tid + q * 256] = acc[q];
}

// ---------------- K5: vf partial = sum_{m in chunk} wf[m]*h[b,m,g*256+d] ----------------
__global__ __launch_bounds__(256) void k_vf_partial(const u16* __restrict__ h,
                                                    const float* __restrict__ wf,
                                                    float* __restrict__ vfp) {
    int mc = blockIdx.x, g = blockIdx.y, b = blockIdx.z;
    int d = threadIdx.x;
    __shared__ float wl[256];
    wl[d] = wf[((size_t)b * 8 + g) * 1024 + mc * 256 + d];
    __syncthreads();
    const u16* hb = h + (size_t)b * 1024 * 2048 + (size_t)(mc * 256) * 2048 + g * 256;
    float acc = 0.f;
    #pragma unroll 8
    for (int m = 0; m < 256; ++m) acc += wl[m] * bf2f(hb[(size_t)m * 2048 + d]);
    vfp[(((size_t)(b * 8 + g)) * 4 + mc) * 256 + d] = acc;
}

// ---------------- K6: finalize vf, center, trace, S(8x8), rank-8 Newton-Schulz ----------------
#define MM8(DST, P, Q) do { if (act) { float s_ = 0.f; \
    _Pragma("unroll") \
    for (int l_ = 0; l_ < 8; ++l_) s_ += P[ii][l_] * Q[l_][jj]; \
    DST[ii][jj] = s_; } __syncthreads(); } while (0)

__global__ __launch_bounds__(256) void k_finalize(const float* __restrict__ vfp,
                                                  const float* __restrict__ u,
                                                  const float* __restrict__ cent,
                                                  const float* __restrict__ bf,
                                                  float* __restrict__ VcOut,
                                                  float* __restrict__ Wrow,
                                                  float* __restrict__ s0) {
    int b = blockIdx.x;
    int tid = threadIdx.x;  // 256
    __shared__ float ul[8][128];
    __shared__ float Vl[256][9];
    __shared__ float red[256];
    __shared__ float Sm[8][8], W1[8][8], W2[8][8], YmL[8][8], ZmL[8][8], ZYL[8][8], FmL[8][8];
    for (int i = tid; i < 1024; i += 256) ul[i >> 7][i & 127] = u[b * 1024 + i];
    __syncthreads();
    int d = tid;
    float bfv = bf[0];
    float vfl[8];
    #pragma unroll
    for (int g = 0; g < 8; ++g) {
        float acc = 0.f;
        #pragma unroll
        for (int mc = 0; mc < 4; ++mc) acc += vfp[(((size_t)(b * 8 + g)) * 4 + mc) * 256 + d];
        float ct = 0.f;
        for (int k = 0; k < 128; ++k) ct += ul[g][k] * cent[k * 256 + d];
        vfl[g] = acc - ct + bfv;
    }
    float mean = 0.f;
    #pragma unroll
    for (int g = 0; g < 8; ++g) mean += vfl[g];
    mean *= 0.125f;
    float trp = 0.f;
    #pragma unroll
    for (int g = 0; g < 8; ++g) { float v = vfl[g] - mean; Vl[d][g] = v; trp += v * v; }
    red[tid] = trp;
    __syncthreads();
    for (int s = 128; s > 0; s >>= 1) { if (tid < s) red[tid] += red[tid + s]; __syncthreads(); }
    float tr = red[0] * 0.125f;  // trace(cov)
    bool act = tid < 64;
    int ii = (tid >> 3) & 7, jj = tid & 7;
    if (act) {
        float sv = 0.f;
        for (int dd = 0; dd < 256; ++dd) sv += Vl[dd][ii] * Vl[dd][jj];
        Sm[ii][jj] = sv / (8.f * tr);
    }
    __syncthreads();
    // representation: mat = a*I + U B U^T, S = U^T U; product (a,P)(c,Q)=(ac, aQ+cP+P S Q)
    if (act) {
        YmL[ii][jj] = (ii == jj ? 1.5f : 0.f) - 0.5f * Sm[ii][jj];
        ZmL[ii][jj] = (ii == jj ? -0.5f : 0.f);
    }
    __syncthreads();
    float ya = 0.f, za = 1.5f;
    MM8(W1, Sm, YmL);
    MM8(W2, ZmL, W1);
    float pa = za * ya;
    if (act) ZYL[ii][jj] = -0.5f * (za * YmL[ii][jj] + ya * ZmL[ii][jj] + W2[ii][jj]);
    __syncthreads();
    float zya = 1.5f - 0.5f * pa;
    MM8(W1, Sm, ZYL);
    MM8(W2, YmL, W1);
    if (act) YmL[ii][jj] = ya * ZYL[ii][jj] + zya * YmL[ii][jj] + W2[ii][jj];
    __syncthreads();
    ya = ya * zya;
    MM8(W1, Sm, ZmL);
    MM8(W2, ZYL, W1);
    if (act) ZmL[ii][jj] = zya * ZmL[ii][jj] + za * ZYL[ii][jj] + W2[ii][jj];
    __syncthreads();
    za = zya * za;
    MM8(W1, Sm, YmL);
    MM8(W2, ZmL, W1);
    float p2a = za * ya;
    if (act) ZYL[ii][jj] = za * YmL[ii][jj] + ya * ZmL[ii][jj] + W2[ii][jj];
    __syncthreads();
    MM8(W1, Sm, ZYL);
    MM8(W2, YmL, W1);
    if (act) FmL[ii][jj] = 0.5f * ((3.f - p2a) * YmL[ii][jj] - ya * ZYL[ii][jj] - W2[ii][jj]);
    __syncthreads();
    float fa = 0.5f * ya * (3.f - p2a);
    float sqtr = sqrtf(tr);
    float scaleF = 1.f / (8.f * sqtr);
    #pragma unroll
    for (int jo = 0; jo < 8; ++jo) {
        float sv = 0.f;
        #pragma unroll
        for (int i = 0; i < 8; ++i) sv += Vl[d][i] * FmL[i][jo];
        Wrow[((size_t)b * 256 + d) * 8 + jo] = sv * scaleF;
    }
    #pragma unroll
    for (int jo = 0; jo < 8; ++jo) VcOut[((size_t)b * 256 + d) * 8 + jo] = Vl[d][jo];
    if (tid == 0) s0[b] = fa * sqtr;
}

// ---------------- K7: triuvec output: R[d,e] = s0*delta + Wrow[d,:].Vc[e,:] ----------------
__global__ __launch_bounds__(256) void k_output(const float* __restrict__ Vc,
                                                const float* __restrict__ Wrow,
                                                const float* __restrict__ s0,
                                                float* __restrict__ out) {
    int dd = blockIdx.x, b = blockIdx.y;
    int e = threadIdx.x;
    __shared__ float Vl[256][9];
    __shared__ float wr[8];
    float4 v0 = *(const float4*)(Vc + ((size_t)b * 256 + e) * 8);
    float4 v1 = *(const float4*)(Vc + ((size_t)b * 256 + e) * 8 + 4);
    Vl[e][0] = v0.x; Vl[e][1] = v0.y; Vl[e][2] = v0.z; Vl[e][3] = v0.w;
    Vl[e][4] = v1.x; Vl[e][5] = v1.y; Vl[e][6] = v1.z; Vl[e][7] = v1.w;
    if (e < 8) wr[e] = Wrow[((size_t)b * 256 + dd) * 8 + e];
    __syncthreads();
    if (e >= dd) {
        float v = (e == dd) ? s0[b] : 0.f;
        #pragma unroll
        for (int j = 0; j < 8; ++j) v += wr[j] * Vl[e][j];
        size_t idx = (size_t)b * 32896 + (size_t)dd * 256 - ((size_t)dd * (dd - 1)) / 2 + (e - dd);
        out[idx] = v;
    }
}

extern "C" void kernel_launch(void* const* d_in, const int* in_sizes, int n_in,
                              void* d_out, int out_size, void* d_ws, size_t ws_size,
                              hipStream_t stream) {
    const float* x    = (const float*)d_in[0];
    const float* cent = (const float*)d_in[1];
    const float* Winp = (const float*)d_in[2];
    const float* binp = (const float*)d_in[3];
    const float* Wg   = (const float*)d_in[4];
    const float* bg   = (const float*)d_in[5];
    const float* Wgk  = (const float*)d_in[6];
    const float* Wf   = (const float*)d_in[8];
    const float* bf   = (const float*)d_in[9];
    float* out = (float*)d_out;
    char* wsb = (char*)d_ws;

    // byte-offset workspace layout
    float* lt    = (float*)(wsb);                        // [4][1024][1024] f32, 16 MB
    u16*   xtnb  = (u16*)(wsb);                          // alias (dead before lt written), 8 MB
    u16*   hb    = (u16*)(wsb + (16ull << 20));          // [4096][2048] bf16, 16 MB
    u16*   winpb = (u16*)(wsb + (32ull << 20));          // [2048][1024] bf16, 4 MB
    u16*   wgkb  = (u16*)(wsb + (36ull << 20));          // [1024][2048] bf16, 4 MB
    float* agT   = (float*)(wsb + (40ull << 20));
    float* wsum  = agT + 32768;
    float* wf    = wsum + 4096;
    float* u     = wf + 32768;
    float* vfp   = u + 4096;
    float* Vc    = vfp + 32768;
    float* Wr    = Vc + 8192;
    float* s0    = Wr + 8192;

    k_transpose_norm<<<dim3(32, 16), 256, 0, stream>>>(x, xtnb);
    k_f2bf<<<2048, 256, 0, stream>>>(Winp, winpb, 2097152);
    k_f2bf<<<2048, 256, 0, stream>>>(Wgk, wgkb, 2097152);
    // GEMM1: h[bm,j] = xtn @ W_inp^T + b_inp -> bf16  (M=4096, N=2048, K=1024)
    k_mfma_gemm<1><<<dim3(16, 32, 1), 256, 0, stream>>>(
        xtnb, winpb, nullptr, hb, binp, 1024, 2048, 0, 0);
    k_alpha_g<<<4096, 64, 0, stream>>>(hb, Wg, bg, agT);
    // GEMM2: logitsT[b][gk][m] = W_gk @ h_b^T -> f32  (M=1024, N=1024, K=2048, z=4)
    // (bias omitted: softmax over m is shift-invariant)
    k_mfma_gemm<0><<<dim3(8, 8, 4), 256, 0, stream>>>(
        wgkb, hb, lt, nullptr, nullptr, 2048, 1024, 2097152LL, 1048576LL);
    k_softmax<<<dim3(1024, 4), 256, 0, stream>>>(lt, agT, wsum);
    k_wf_u<<<32, 256, 0, stream>>>(lt, wsum, Wf, wf, u);
    k_vf_partial<<<dim3(4, 8, 4), 256, 0, stream>>>(hb, wf, vfp);
    k_finalize<<<4, 256, 0, stream>>>(vfp, u, cent, bf, Vc, Wr, s0);
    k_output<<<dim3(256, 4), 256, 0, stream>>>(Vc, Wr, s0, out);
}